// Round 3
// baseline (198.979 us; speedup 1.0000x reference)
//
#include <hip/hip_runtime.h>

#define BATCHES 8
#define NPTS    100000
#define NPOINT  64
#define BPB     16                    // blocks per batch
#define NTHREADS 1024
#define TPB     (BPB * NTHREADS)      // threads per batch = 16384
#define KMAX    7                     // ceil(NPTS / TPB)
#define TAILN   (NPTS - (KMAX - 1) * TPB)

// workspace layout (zeroed per call by hipMemsetAsync)
#define WS_BARY_OFF 0                                    // [B][BPB][3] double = 3072 B
#define WS_CNT_OFF  3072                                 // [B] u32
#define WS_SLOT_OFF 4096                                 // [B][NPOINT][BPB] u64 = 65536 B
#define WS_CTRL_BYTES (WS_SLOT_OFF + BATCHES * NPOINT * BPB * 8)

// contraction-free f32 squared distance, numpy sum order (dx*dx + dy*dy) + dz*dz
__device__ __forceinline__ float sq3(float dx, float dy, float dz) {
    return __fadd_rn(__fadd_rn(__fmul_rn(dx, dx), __fmul_rn(dy, dy)), __fmul_rn(dz, dz));
}

__global__ __launch_bounds__(NTHREADS, 4)
void fps_kernel(const float* __restrict__ xyz, float* __restrict__ out,
                unsigned char* __restrict__ ws)
{
    double* baryPart = (double*)(ws + WS_BARY_OFF);
    unsigned int* cnt = (unsigned int*)(ws + WS_CNT_OFF);
    unsigned long long* slots = (unsigned long long*)(ws + WS_SLOT_OFF);

    const int b    = blockIdx.x >> 4;
    const int blk  = blockIdx.x & (BPB - 1);
    const int tid  = threadIdx.x;
    const int wid  = tid >> 6;
    const int lane = tid & 63;
    const int t    = blk * NTHREADS + tid;

    const float* xb = xyz + (size_t)b * NPTS * 3;

    __shared__ float centC[NPOINT][3];
    __shared__ double bred[16][3];
    __shared__ unsigned long long kcand[2][16];   // per-wave candidates, parity-buffered
    __shared__ unsigned int wflag[2];             // winner broadcast: (tag<<18)|idx
    __shared__ float s_bc[3];

    float px[KMAX], py[KMAX], pz[KMAX], dist[KMAX];
    const int nk = (t < TAILN) ? KMAX : (KMAX - 1);

    // init LDS control words (before any use; barriers below publish)
    if (tid < 32) kcand[tid >> 4][tid & 15] = 0ull;
    if (tid == 32) { wflag[0] = 0u; wflag[1] = 0u; }

    // ---- load points into registers; double partial sums for the mean ----
    double sx = 0.0, sy = 0.0, sz = 0.0;
    #pragma unroll
    for (int k = 0; k < KMAX; k++) {
        if (k < nk) {
            int p = t + k * TPB;
            float x = xb[p * 3 + 0], y = xb[p * 3 + 1], z = xb[p * 3 + 2];
            px[k] = x; py[k] = y; pz[k] = z; dist[k] = 1e10f;
            sx += (double)x; sy += (double)y; sz += (double)z;
        }
    }
    for (int off = 32; off > 0; off >>= 1) {
        sx += __shfl_down(sx, off); sy += __shfl_down(sy, off); sz += __shfl_down(sz, off);
    }
    if (lane == 0) { bred[wid][0] = sx; bred[wid][1] = sy; bred[wid][2] = sz; }
    __syncthreads();
    if (tid == 0) {
        double ax = 0, ay = 0, az = 0;
        for (int w = 0; w < 16; w++) { ax += bred[w][0]; ay += bred[w][1]; az += bred[w][2]; }
        double* dst = baryPart + ((size_t)b * BPB + blk) * 3;
        dst[0] = ax; dst[1] = ay; dst[2] = az;
        __hip_atomic_fetch_add(&cnt[b], 1u, __ATOMIC_ACQ_REL, __HIP_MEMORY_SCOPE_AGENT);
        while (__hip_atomic_load(&cnt[b], __ATOMIC_ACQUIRE, __HIP_MEMORY_SCOPE_AGENT) < BPB)
            __builtin_amdgcn_s_sleep(2);
        double mx = 0, my = 0, mz = 0;
        for (int q = 0; q < BPB; q++) {       // deterministic fixed order
            const double* s2 = baryPart + ((size_t)b * BPB + q) * 3;
            mx += s2[0]; my += s2[1]; mz += s2[2];
        }
        s_bc[0] = (float)(mx / (double)NPTS);
        s_bc[1] = (float)(my / (double)NPTS);
        s_bc[2] = (float)(mz / (double)NPTS);
    }
    __syncthreads();
    const float bx = s_bc[0], by = s_bc[1], bz = s_bc[2];

    // ---- candidate 0: argmax of distance to barycenter ----
    unsigned long long key = 0;
    #pragma unroll
    for (int k = 0; k < KMAX; k++) {
        if (k < nk) {
            int p = t + k * TPB;
            float d = sq3(__fsub_rn(px[k], bx), __fsub_rn(py[k], by), __fsub_rn(pz[k], bz));
            unsigned long long kk = (((unsigned long long)__float_as_uint(d)) << 32)
                                    | (unsigned)(0xFFFFFFFFu - (unsigned)p);
            if (kk > key) key = kk;
        }
    }

    // ================= 64 exchanges, barrier-free (LDS flag handoffs) =================
    for (int e = 0; e < NPOINT; e++) {
        const int par = e & 1;
        // per-wave reduce + post candidate
        for (int off = 32; off > 0; off >>= 1) {
            unsigned long long o = __shfl_down(key, off); if (o > key) key = o;
        }
        if (lane == 0)
            __hip_atomic_store(&kcand[par][wid], key, __ATOMIC_RELEASE, __HIP_MEMORY_SCOPE_WORKGROUP);

        // control wave: gather block candidate, global exchange, publish winner
        if (wid == 0) {
            unsigned long long v = 0;
            if (lane < 16) {
                unsigned long long kk;
                while ((kk = __hip_atomic_load(&kcand[par][lane], __ATOMIC_ACQUIRE,
                                               __HIP_MEMORY_SCOPE_WORKGROUP)) == 0ull)
                    __builtin_amdgcn_s_sleep(1);
                __hip_atomic_store(&kcand[par][lane], 0ull, __ATOMIC_RELAXED,
                                   __HIP_MEMORY_SCOPE_WORKGROUP);
                v = kk;
            }
            for (int m = 8; m > 0; m >>= 1) {
                unsigned long long o = __shfl_xor(v, m, 16); if (o > v) v = o;
            }
            unsigned long long* row = &slots[((size_t)b * NPOINT + e) * BPB];
            if (lane == 0)
                __hip_atomic_store(&row[blk], v, __ATOMIC_RELAXED, __HIP_MEMORY_SCOPE_AGENT);
            unsigned long long w = 0;
            if (lane < BPB) {
                while ((w = __hip_atomic_load(&row[lane], __ATOMIC_RELAXED,
                                              __HIP_MEMORY_SCOPE_AGENT)) == 0ull)
                    __builtin_amdgcn_s_sleep(1);
            }
            for (int m = 8; m > 0; m >>= 1) {
                unsigned long long o = __shfl_xor(w, m, 16); if (o > w) w = o;
            }
            if (lane == 0) {
                unsigned f = 0xFFFFFFFFu - (unsigned)(w & 0xFFFFFFFFull);
                __hip_atomic_store(&wflag[par], (((unsigned)(e + 1)) << 18) | f,
                                   __ATOMIC_RELEASE, __HIP_MEMORY_SCOPE_WORKGROUP);
            }
        }

        // everyone: wait for this round's winner
        unsigned vfl;
        while (((vfl = __hip_atomic_load(&wflag[par], __ATOMIC_ACQUIRE,
                                         __HIP_MEMORY_SCOPE_WORKGROUP)) >> 18) != (unsigned)(e + 1))
            __builtin_amdgcn_s_sleep(1);
        const int f = (int)(vfl & 0x3FFFFu);

        // housekeeping off the critical path (wave 1)
        if (wid == 1 && lane == 0) {
            float cx = xb[f * 3 + 0], cy = xb[f * 3 + 1], cz = xb[f * 3 + 2];
            centC[e][0] = cx; centC[e][1] = cy; centC[e][2] = cz;
            if (blk == 0) {
                out[((size_t)b * NPOINT + e) * 3 + 0] = cx;
                out[((size_t)b * NPOINT + e) * 3 + 1] = cy;
                out[((size_t)b * NPOINT + e) * 3 + 2] = cz;
                out[(size_t)BATCHES * NPOINT * 3 + b * NPOINT + e] = (float)f;
            }
        }
        if (e == NPOINT - 1) break;

        // distance update vs winner + next candidate
        const float cx = xb[f * 3 + 0], cy = xb[f * 3 + 1], cz = xb[f * 3 + 2];
        key = 0;
        #pragma unroll
        for (int k = 0; k < KMAX; k++) {
            if (k < nk) {
                int p = t + k * TPB;
                float d = sq3(__fsub_rn(px[k], cx), __fsub_rn(py[k], cy), __fsub_rn(pz[k], cz));
                float nd = (p == f) ? 0.0f : fminf(dist[k], d);
                dist[k] = nd;
                unsigned long long kk = (((unsigned long long)__float_as_uint(nd)) << 32)
                                        | (unsigned)(0xFFFFFFFFu - (unsigned)p);
                if (kk > key) key = kk;
            }
        }
    }
    __syncthreads();                           // publish centC to all waves

    // ---- nearest-centroid assignment (centroids in LDS) ----
    float* outClust = out + (size_t)BATCHES * NPOINT * 3 + (size_t)BATCHES * NPOINT;
    float bestd[KMAX]; int besti[KMAX];
    #pragma unroll
    for (int k = 0; k < KMAX; k++) { bestd[k] = 3.4e38f; besti[k] = 0; }
    for (int j = 0; j < NPOINT; j++) {
        float cx = centC[j][0], cy = centC[j][1], cz = centC[j][2];
        #pragma unroll
        for (int k = 0; k < KMAX; k++) {
            if (k < nk) {
                float d = sq3(__fsub_rn(px[k], cx), __fsub_rn(py[k], cy), __fsub_rn(pz[k], cz));
                if (d < bestd[k]) { bestd[k] = d; besti[k] = j; }
            }
        }
    }
    #pragma unroll
    for (int k = 0; k < KMAX; k++)
        if (k < nk) outClust[(size_t)b * NPTS + t + k * TPB] = (float)besti[k];
}

extern "C" void kernel_launch(void* const* d_in, const int* in_sizes, int n_in,
                              void* d_out, int out_size, void* d_ws, size_t ws_size,
                              hipStream_t stream) {
    const float* xyz = (const float*)d_in[0];
    float* out = (float*)d_out;
    hipMemsetAsync(d_ws, 0, WS_CTRL_BYTES, stream);
    fps_kernel<<<dim3(BATCHES * BPB), dim3(NTHREADS), 0, stream>>>(
        xyz, out, (unsigned char*)d_ws);
}